// Round 8
// baseline (67.957 us; speedup 1.0000x reference)
//
#include <hip/hip_runtime.h>

// Periodogram: out[b,m] = (re^2 + im^2)/N,  re = aC + bS, im = bC - aS
// f16 MFMA GEMMs. Trig staged to LDS, generated by per-thread rotation
// recurrence; XOR-swizzled conflict-free LDS; NS by sign-flip after read.
// NEW (r7): anti-phase stagger of the 2 co-resident blocks per CU via a
// one-time s_sleep, so one block's staging VALU hides under the other's MFMA.

typedef __fp16 half8 __attribute__((ext_vector_type(8)));
typedef __fp16 half2v __attribute__((ext_vector_type(2)));
typedef float f32x4 __attribute__((ext_vector_type(4)));

#define B_SZ 512
#define N_SZ 1024
#define M_SZ 16384
#define BT 128
#define MT 128
#define KT 32

union U2  { half2v h2[2]; uint2 u; };
union H8U { half8 v; uint4 u; };

__global__ __launch_bounds__(256, 2)
void periodogram_kernel(const float* __restrict__ x, const float* __restrict__ xgrid,
                        float* __restrict__ out) {
    __shared__ __align__(16) unsigned char smem[4 * 8192];  // A | B | C | S
    const int tid  = (int)threadIdx.x;
    const int lane = tid & 63;
    const int w    = tid >> 6;
    const int bid  = (int)blockIdx.x;
    const int b0 = (bid & 3) * BT;
    const int m0 = (bid >> 2) * MT;

    // ---- anti-phase stagger: offset one block of each same-CU pair by
    // ~1400 cy. Pairing is (2c,2c+1) or (c,c+256) depending on dispatch;
    // bit0 XOR bit8 separates both. One-time delay, correctness-neutral.
    if (((bid ^ (bid >> 8)) & 1) != 0) __builtin_amdgcn_s_sleep(22);

    // ---- staging assignment: thread -> rows {row8+32*rep}, k-chunk kk ----
    const int row8 = tid >> 3;          // 0..31
    const int kk   = (tid & 7) * 4;     // 0,4,...,28
    const int g    = kk >> 3;           // 0..3
    const int kkh  = (kk >> 2) & 1;     // which 8B half of the 16B cell

    unsigned woff[4];
    const float* srcA[4];
    float C1[4], S1[4], C32[4], S32[4], c0v[4], s0v[4];
#pragma unroll
    for (int rep = 0; rep < 4; ++rep) {
        const int row = row8 + rep * 32;
        const int rb = row >> 4, r16 = row & 15;
        woff[rep] = (unsigned)(rb * 1024 + ((g * 16 + (r16 ^ (g << 1))) << 4) + kkh * 8);
        srcA[rep] = x + (size_t)(b0 + row) * 2048 + kk;
        const float xg = xgrid[m0 + row];
        // Delta-1 rotation (per k)
        const float f1 = xg - floorf(xg);
        C1[rep] = __builtin_amdgcn_cosf(f1);
        S1[rep] = __builtin_amdgcn_sinf(f1);
        // Delta-32 rotation (per K-step); xg*32 is exact
        float p32 = xg * 32.0f; p32 -= floorf(p32);
        C32[rep] = __builtin_amdgcn_cosf(p32);
        S32[rep] = __builtin_amdgcn_sinf(p32);
        // state at k = kk (residual-corrected phase)
        const float kf = (float)kk;
        const float pk = xg * kf;
        const float e  = __builtin_fmaf(xg, kf, -pk);
        const float f  = (pk - floorf(pk)) + e;
        c0v[rep] = __builtin_amdgcn_cosf(f);
        s0v[rep] = __builtin_amdgcn_sinf(f);
    }

    f32x4 accRe[4][4], accIm[4][4];
#pragma unroll
    for (int i = 0; i < 4; ++i)
#pragma unroll
        for (int j = 0; j < 4; ++j) { accRe[i][j] = (f32x4)0.0f; accIm[i][j] = (f32x4)0.0f; }

    // ---- fragment read bases (swizzled lane->cell) ----
    const int wr = (w >> 1) * 64;
    const int wc = (w & 1) * 64;
    const unsigned roff  = (unsigned)((lane ^ ((lane >> 4) << 1)) << 4);
    const unsigned aBase = 0u     + ((unsigned)(wr >> 4) << 10) + roff;
    const unsigned bBase = 8192u  + ((unsigned)(wr >> 4) << 10) + roff;
    const unsigned cBase = 16384u + ((unsigned)(wc >> 4) << 10) + roff;
    const unsigned sBase = 24576u + ((unsigned)(wc >> 4) << 10) + roff;

    for (int t = 0; t < N_SZ / KT; ++t) {
        const int k0 = t * KT;
        // ---- issue global loads + trig VALU before the barrier ----
        float4 va[4], vb[4];
#pragma unroll
        for (int rep = 0; rep < 4; ++rep) {
            va[rep] = *(const float4*)(srcA[rep] + k0);
            vb[rep] = *(const float4*)(srcA[rep] + k0 + 1024);
        }
        uint2 cw[4], sw[4];
#pragma unroll
        for (int rep = 0; rep < 4; ++rep) {
            const float c0 = c0v[rep], s0 = s0v[rep];
            const float c1 = __builtin_fmaf(c0, C1[rep], -(s0 * S1[rep]));
            const float s1 = __builtin_fmaf(s0, C1[rep],  (c0 * S1[rep]));
            const float c2 = __builtin_fmaf(c1, C1[rep], -(s1 * S1[rep]));
            const float s2 = __builtin_fmaf(s1, C1[rep],  (c1 * S1[rep]));
            const float c3 = __builtin_fmaf(c2, C1[rep], -(s2 * S1[rep]));
            const float s3 = __builtin_fmaf(s2, C1[rep],  (c2 * S1[rep]));
            U2 pc, ps;
            pc.h2[0] = __builtin_amdgcn_cvt_pkrtz(c0, c1);
            pc.h2[1] = __builtin_amdgcn_cvt_pkrtz(c2, c3);
            ps.h2[0] = __builtin_amdgcn_cvt_pkrtz(s0, s1);
            ps.h2[1] = __builtin_amdgcn_cvt_pkrtz(s2, s3);
            cw[rep] = pc.u; sw[rep] = ps.u;
            // advance state by Delta-32
            c0v[rep] = __builtin_fmaf(c0, C32[rep], -(s0 * S32[rep]));
            s0v[rep] = __builtin_fmaf(s0, C32[rep],  (c0 * S32[rep]));
        }
        __syncthreads();   // previous iteration's fragment reads done
        // ---- stage to LDS ----
#pragma unroll
        for (int rep = 0; rep < 4; ++rep) {
            U2 pa, pb;
            pa.h2[0] = __builtin_amdgcn_cvt_pkrtz(va[rep].x, va[rep].y);
            pa.h2[1] = __builtin_amdgcn_cvt_pkrtz(va[rep].z, va[rep].w);
            pb.h2[0] = __builtin_amdgcn_cvt_pkrtz(vb[rep].x, vb[rep].y);
            pb.h2[1] = __builtin_amdgcn_cvt_pkrtz(vb[rep].z, vb[rep].w);
            *(uint2*)(smem + 0     + woff[rep]) = pa.u;
            *(uint2*)(smem + 8192  + woff[rep]) = pb.u;
            *(uint2*)(smem + 16384 + woff[rep]) = cw[rep];
            *(uint2*)(smem + 24576 + woff[rep]) = sw[rep];
        }
        __syncthreads();
        // ---- compute ----
        half8 fa[4], fb[4];
#pragma unroll
        for (int fm = 0; fm < 4; ++fm) {
            fa[fm] = *(const half8*)(smem + aBase + fm * 1024);
            fb[fm] = *(const half8*)(smem + bBase + fm * 1024);
        }
#pragma unroll
        for (int fn = 0; fn < 4; ++fn) {
            const half8 fc = *(const half8*)(smem + cBase + fn * 1024);
            H8U fsU;  fsU.v = *(const half8*)(smem + sBase + fn * 1024);
            H8U fnsU;
            fnsU.u.x = fsU.u.x ^ 0x80008000u;
            fnsU.u.y = fsU.u.y ^ 0x80008000u;
            fnsU.u.z = fsU.u.z ^ 0x80008000u;
            fnsU.u.w = fsU.u.w ^ 0x80008000u;
#pragma unroll
            for (int fm = 0; fm < 4; ++fm) {
                accRe[fm][fn] = __builtin_amdgcn_mfma_f32_16x16x32_f16(fa[fm], fc,     accRe[fm][fn], 0, 0, 0);
                accRe[fm][fn] = __builtin_amdgcn_mfma_f32_16x16x32_f16(fb[fm], fsU.v,  accRe[fm][fn], 0, 0, 0);
                accIm[fm][fn] = __builtin_amdgcn_mfma_f32_16x16x32_f16(fb[fm], fc,     accIm[fm][fn], 0, 0, 0);
                accIm[fm][fn] = __builtin_amdgcn_mfma_f32_16x16x32_f16(fa[fm], fnsU.v, accIm[fm][fn], 0, 0, 0);
            }
        }
    }

    // ---- epilogue: out = (re^2 + im^2)/N ----
    // D frag layout (measured m89): col = lane&15, row = (lane>>4)*4 + reg
    const float inv = 1.0f / (float)N_SZ;
    const int orow0 = b0 + wr + ((lane >> 4) << 2);
    const int ocol0 = m0 + wc + (lane & 15);
#pragma unroll
    for (int fm = 0; fm < 4; ++fm)
#pragma unroll
        for (int fn = 0; fn < 4; ++fn) {
            const f32x4 r = accRe[fm][fn];
            const f32x4 im = accIm[fm][fn];
            const int col = ocol0 + fn * 16;
#pragma unroll
            for (int j = 0; j < 4; ++j) {
                const int row = orow0 + fm * 16 + j;
                out[(size_t)row * M_SZ + col] = (r[j] * r[j] + im[j] * im[j]) * inv;
            }
        }
}

extern "C" void kernel_launch(void* const* d_in, const int* in_sizes, int n_in,
                              void* d_out, int out_size, void* d_ws, size_t ws_size,
                              hipStream_t stream) {
    const float* x     = (const float*)d_in[0];
    const float* xgrid = (const float*)d_in[1];
    float* out = (float*)d_out;
    dim3 grid(B_SZ / BT * (M_SZ / MT));   // 4 * 128 = 512 blocks
    dim3 block(256);
    periodogram_kernel<<<grid, block, 0, stream>>>(x, xgrid, out);
}

// Round 9
// 67.590 us; speedup vs baseline: 1.0054x; 1.0054x over previous
//
#include <hip/hip_runtime.h>

// Periodogram: out[b,m] = (re^2 + im^2)/N,  re = aC + bS, im = bC - aS
// f16 MFMA GEMMs; trig via per-thread rotation recurrence; XOR-swizzled LDS.
// r9: double-buffered LDS, ONE barrier per K-step (T3-minimum), with
// T14 write-late staging: loads issued early, A/B cvt+write after MFMA.

typedef __fp16 half8 __attribute__((ext_vector_type(8)));
typedef __fp16 half2v __attribute__((ext_vector_type(2)));
typedef float f32x4 __attribute__((ext_vector_type(4)));

#define B_SZ 512
#define N_SZ 1024
#define M_SZ 16384
#define BT 128
#define MT 128
#define KT 32
#define BUF 32768u

union U2  { half2v h2[2]; uint2 u; };
union H8U { half8 v; uint4 u; };

__global__ __launch_bounds__(256, 2)
void periodogram_kernel(const float* __restrict__ x, const float* __restrict__ xgrid,
                        float* __restrict__ out) {
    // two buffers, each: A | B | C | S (8 KB each)
    __shared__ __align__(16) unsigned char smem[2 * BUF];
    const int tid  = (int)threadIdx.x;
    const int lane = tid & 63;
    const int w    = tid >> 6;
    const int bid  = (int)blockIdx.x;
    const int b0 = (bid & 3) * BT;
    const int m0 = (bid >> 2) * MT;

    // ---- staging assignment: thread -> rows {row8+32*rep}, k-chunk kk ----
    const int row8 = tid >> 3;          // 0..31
    const int kk   = (tid & 7) * 4;     // 0,4,...,28
    const int g    = kk >> 3;           // 0..3
    const int kkh  = (kk >> 2) & 1;     // 8B half of the 16B cell

    unsigned woff[4];
    const float* srcA[4];
    float C1[4], S1[4], C32[4], S32[4], c0v[4], s0v[4];
#pragma unroll
    for (int rep = 0; rep < 4; ++rep) {
        const int row = row8 + rep * 32;
        const int rb = row >> 4, r16 = row & 15;
        woff[rep] = (unsigned)(rb * 1024 + ((g * 16 + (r16 ^ (g << 1))) << 4) + kkh * 8);
        srcA[rep] = x + (size_t)(b0 + row) * 2048 + kk;
        const float xg = xgrid[m0 + row];
        const float f1 = xg - floorf(xg);
        C1[rep] = __builtin_amdgcn_cosf(f1);
        S1[rep] = __builtin_amdgcn_sinf(f1);
        float p32 = xg * 32.0f; p32 -= floorf(p32);
        C32[rep] = __builtin_amdgcn_cosf(p32);
        S32[rep] = __builtin_amdgcn_sinf(p32);
        const float kf = (float)kk;
        const float pk = xg * kf;
        const float e  = __builtin_fmaf(xg, kf, -pk);
        const float f  = (pk - floorf(pk)) + e;
        c0v[rep] = __builtin_amdgcn_cosf(f);
        s0v[rep] = __builtin_amdgcn_sinf(f);
    }

    f32x4 accRe[4][4], accIm[4][4];
#pragma unroll
    for (int i = 0; i < 4; ++i)
#pragma unroll
        for (int j = 0; j < 4; ++j) { accRe[i][j] = (f32x4)0.0f; accIm[i][j] = (f32x4)0.0f; }

    // ---- fragment read bases (swizzled lane->cell), relative to buffer ----
    const int wr = (w >> 1) * 64;
    const int wc = (w & 1) * 64;
    const unsigned roff  = (unsigned)((lane ^ ((lane >> 4) << 1)) << 4);
    const unsigned aBase = 0u     + ((unsigned)(wr >> 4) << 10) + roff;
    const unsigned bBase = 8192u  + ((unsigned)(wr >> 4) << 10) + roff;
    const unsigned cBase = 16384u + ((unsigned)(wc >> 4) << 10) + roff;
    const unsigned sBase = 24576u + ((unsigned)(wc >> 4) << 10) + roff;

    // ---------------- prologue: stage K-step 0 into buffer 0 ----------------
    {
#pragma unroll
        for (int rep = 0; rep < 4; ++rep) {
            const float4 va = *(const float4*)(srcA[rep]);
            const float4 vb = *(const float4*)(srcA[rep] + 1024);
            const float c0 = c0v[rep], s0 = s0v[rep];
            const float c1 = __builtin_fmaf(c0, C1[rep], -(s0 * S1[rep]));
            const float s1 = __builtin_fmaf(s0, C1[rep],  (c0 * S1[rep]));
            const float c2 = __builtin_fmaf(c1, C1[rep], -(s1 * S1[rep]));
            const float s2 = __builtin_fmaf(s1, C1[rep],  (c1 * S1[rep]));
            const float c3 = __builtin_fmaf(c2, C1[rep], -(s2 * S1[rep]));
            const float s3 = __builtin_fmaf(s2, C1[rep],  (c2 * S1[rep]));
            U2 pa, pb, pc, ps;
            pa.h2[0] = __builtin_amdgcn_cvt_pkrtz(va.x, va.y);
            pa.h2[1] = __builtin_amdgcn_cvt_pkrtz(va.z, va.w);
            pb.h2[0] = __builtin_amdgcn_cvt_pkrtz(vb.x, vb.y);
            pb.h2[1] = __builtin_amdgcn_cvt_pkrtz(vb.z, vb.w);
            pc.h2[0] = __builtin_amdgcn_cvt_pkrtz(c0, c1);
            pc.h2[1] = __builtin_amdgcn_cvt_pkrtz(c2, c3);
            ps.h2[0] = __builtin_amdgcn_cvt_pkrtz(s0, s1);
            ps.h2[1] = __builtin_amdgcn_cvt_pkrtz(s2, s3);
            *(uint2*)(smem + 0     + woff[rep]) = pa.u;
            *(uint2*)(smem + 8192  + woff[rep]) = pb.u;
            *(uint2*)(smem + 16384 + woff[rep]) = pc.u;
            *(uint2*)(smem + 24576 + woff[rep]) = ps.u;
            c0v[rep] = __builtin_fmaf(c0, C32[rep], -(s0 * S32[rep]));
            s0v[rep] = __builtin_fmaf(s0, C32[rep],  (c0 * S32[rep]));
        }
    }
    __syncthreads();

    for (int t = 0; t < N_SZ / KT; ++t) {
        const unsigned cur = (unsigned)(t & 1) * BUF;
        const unsigned nxt = cur ^ BUF;
        const bool haveNext = (t < N_SZ / KT - 1);
        // ---- issue next-tile global loads early (land under MFMA) ----
        float4 va[4], vb[4];
        if (haveNext) {
            const int k0 = (t + 1) * KT;
#pragma unroll
            for (int rep = 0; rep < 4; ++rep) {
                va[rep] = *(const float4*)(srcA[rep] + k0);
                vb[rep] = *(const float4*)(srcA[rep] + k0 + 1024);
            }
            // ---- trig for next tile (VALU only) + write C/S to nxt ----
#pragma unroll
            for (int rep = 0; rep < 4; ++rep) {
                const float c0 = c0v[rep], s0 = s0v[rep];
                const float c1 = __builtin_fmaf(c0, C1[rep], -(s0 * S1[rep]));
                const float s1 = __builtin_fmaf(s0, C1[rep],  (c0 * S1[rep]));
                const float c2 = __builtin_fmaf(c1, C1[rep], -(s1 * S1[rep]));
                const float s2 = __builtin_fmaf(s1, C1[rep],  (c1 * S1[rep]));
                const float c3 = __builtin_fmaf(c2, C1[rep], -(s2 * S1[rep]));
                const float s3 = __builtin_fmaf(s2, C1[rep],  (c2 * S1[rep]));
                U2 pc, ps;
                pc.h2[0] = __builtin_amdgcn_cvt_pkrtz(c0, c1);
                pc.h2[1] = __builtin_amdgcn_cvt_pkrtz(c2, c3);
                ps.h2[0] = __builtin_amdgcn_cvt_pkrtz(s0, s1);
                ps.h2[1] = __builtin_amdgcn_cvt_pkrtz(s2, s3);
                *(uint2*)(smem + nxt + 16384 + woff[rep]) = pc.u;
                *(uint2*)(smem + nxt + 24576 + woff[rep]) = ps.u;
                c0v[rep] = __builtin_fmaf(c0, C32[rep], -(s0 * S32[rep]));
                s0v[rep] = __builtin_fmaf(s0, C32[rep],  (c0 * S32[rep]));
            }
        }
        // ---- compute tile t from cur ----
        half8 fa[4], fb[4];
#pragma unroll
        for (int fm = 0; fm < 4; ++fm) {
            fa[fm] = *(const half8*)(smem + cur + aBase + fm * 1024);
            fb[fm] = *(const half8*)(smem + cur + bBase + fm * 1024);
        }
#pragma unroll
        for (int fn = 0; fn < 4; ++fn) {
            const half8 fc = *(const half8*)(smem + cur + cBase + fn * 1024);
            H8U fsU;  fsU.v = *(const half8*)(smem + cur + sBase + fn * 1024);
            H8U fnsU;
            fnsU.u.x = fsU.u.x ^ 0x80008000u;
            fnsU.u.y = fsU.u.y ^ 0x80008000u;
            fnsU.u.z = fsU.u.z ^ 0x80008000u;
            fnsU.u.w = fsU.u.w ^ 0x80008000u;
#pragma unroll
            for (int fm = 0; fm < 4; ++fm) {
                accRe[fm][fn] = __builtin_amdgcn_mfma_f32_16x16x32_f16(fa[fm], fc,     accRe[fm][fn], 0, 0, 0);
                accRe[fm][fn] = __builtin_amdgcn_mfma_f32_16x16x32_f16(fb[fm], fsU.v,  accRe[fm][fn], 0, 0, 0);
                accIm[fm][fn] = __builtin_amdgcn_mfma_f32_16x16x32_f16(fb[fm], fc,     accIm[fm][fn], 0, 0, 0);
                accIm[fm][fn] = __builtin_amdgcn_mfma_f32_16x16x32_f16(fa[fm], fnsU.v, accIm[fm][fn], 0, 0, 0);
            }
        }
        // ---- write-late: A/B cvt + store to nxt (loads landed under MFMA) ----
        if (haveNext) {
#pragma unroll
            for (int rep = 0; rep < 4; ++rep) {
                U2 pa, pb;
                pa.h2[0] = __builtin_amdgcn_cvt_pkrtz(va[rep].x, va[rep].y);
                pa.h2[1] = __builtin_amdgcn_cvt_pkrtz(va[rep].z, va[rep].w);
                pb.h2[0] = __builtin_amdgcn_cvt_pkrtz(vb[rep].x, vb[rep].y);
                pb.h2[1] = __builtin_amdgcn_cvt_pkrtz(vb[rep].z, vb[rep].w);
                *(uint2*)(smem + nxt + 0    + woff[rep]) = pa.u;
                *(uint2*)(smem + nxt + 8192 + woff[rep]) = pb.u;
            }
            __syncthreads();   // nxt fully staged; all waves done reading cur
        }
    }

    // ---- epilogue: out = (re^2 + im^2)/N ----
    // D frag layout (measured m89): col = lane&15, row = (lane>>4)*4 + reg
    const float inv = 1.0f / (float)N_SZ;
    const int orow0 = b0 + wr + ((lane >> 4) << 2);
    const int ocol0 = m0 + wc + (lane & 15);
#pragma unroll
    for (int fm = 0; fm < 4; ++fm)
#pragma unroll
        for (int fn = 0; fn < 4; ++fn) {
            const f32x4 r = accRe[fm][fn];
            const f32x4 im = accIm[fm][fn];
            const int col = ocol0 + fn * 16;
#pragma unroll
            for (int j = 0; j < 4; ++j) {
                const int row = orow0 + fm * 16 + j;
                out[(size_t)row * M_SZ + col] = (r[j] * r[j] + im[j] * im[j]) * inv;
            }
        }
}

extern "C" void kernel_launch(void* const* d_in, const int* in_sizes, int n_in,
                              void* d_out, int out_size, void* d_ws, size_t ws_size,
                              hipStream_t stream) {
    const float* x     = (const float*)d_in[0];
    const float* xgrid = (const float*)d_in[1];
    float* out = (float*)d_out;
    dim3 grid(B_SZ / BT * (M_SZ / MT));   // 4 * 128 = 512 blocks
    dim3 block(256);
    periodogram_kernel<<<grid, block, 0, stream>>>(x, xgrid, out);
}